// Round 1
// 7640.363 us; speedup vs baseline: 1.5462x; 1.5462x over previous
//
#include <hip/hip_runtime.h>
#include <hip/hip_cooperative_groups.h>
#include <cmath>

namespace cg = cooperative_groups;

#define IN_DIM 1024
#define HD 256
#define G4H 1024
#define BB 64
#define TT 512
#define NCLS 8

/* h rings: 3 layers x 4 slots, 16384 floats per slot.
 * PAIR-INTERLEAVED slot layout: element (k,b) lives at (k>>1)*128 + b*2 + (k&1)
 * -> consumers load h as 8B (float2) agent atomics, fully coalesced. */
#define SLOT_STRIDE (HD * BB)          /* 16384 floats */
#define LAYER_STRIDE (4 * SLOT_STRIDE) /* 65536 floats */

__device__ __forceinline__ float sigmoidf_(float x) {
    return 1.0f / (1.0f + __expf(-x));
}
__device__ __forceinline__ float tanhf_(float x) {
    return 2.0f / (1.0f + __expf(-2.0f * x)) - 1.0f;
}
__device__ __forceinline__ float2 ld_agent2(const float* p) {
    unsigned long long r = __hip_atomic_load((const unsigned long long*)p,
                                             __ATOMIC_RELAXED, __HIP_MEMORY_SCOPE_AGENT);
    union { unsigned long long u; float2 f; } cv;
    cv.u = r;
    return cv.f;
}
__device__ __forceinline__ void st_agent(float* p, float v) {
    __hip_atomic_store(p, v, __ATOMIC_RELAXED, __HIP_MEMORY_SCOPE_AGENT);
}

/* ---------------- Kernel 1: xg0 = x @ Wih0^T + b0, stored (B*T, 4H) ---------------- */
#define GBM 128
#define GBN 128
#define GBK 16

__global__ __launch_bounds__(256) void xg0_gemm(const float* __restrict__ x,
                                                const float* __restrict__ Wih0,
                                                const float* __restrict__ b0,
                                                float* __restrict__ xg0) {
    __shared__ float As[GBK][GBM];
    __shared__ float Bs[GBK][GBN];
    const int m0 = blockIdx.y * GBM;
    const int n0 = blockIdx.x * GBN;
    const int tid = threadIdx.x;
    const int tx = tid & 15;
    const int ty = tid >> 4;
    const int lr = tid >> 1;
    const int lk = (tid & 1) * 8;
    float acc[8][8] = {};
    for (int k0 = 0; k0 < IN_DIM; k0 += GBK) {
        const float4 a0 = *(const float4*)&x[(size_t)(m0 + lr) * IN_DIM + k0 + lk];
        const float4 a1 = *(const float4*)&x[(size_t)(m0 + lr) * IN_DIM + k0 + lk + 4];
        const float4 w0 = *(const float4*)&Wih0[(size_t)(n0 + lr) * IN_DIM + k0 + lk];
        const float4 w1 = *(const float4*)&Wih0[(size_t)(n0 + lr) * IN_DIM + k0 + lk + 4];
        __syncthreads();
        As[lk + 0][lr] = a0.x; As[lk + 1][lr] = a0.y; As[lk + 2][lr] = a0.z; As[lk + 3][lr] = a0.w;
        As[lk + 4][lr] = a1.x; As[lk + 5][lr] = a1.y; As[lk + 6][lr] = a1.z; As[lk + 7][lr] = a1.w;
        Bs[lk + 0][lr] = w0.x; Bs[lk + 1][lr] = w0.y; Bs[lk + 2][lr] = w0.z; Bs[lk + 3][lr] = w0.w;
        Bs[lk + 4][lr] = w1.x; Bs[lk + 5][lr] = w1.y; Bs[lk + 6][lr] = w1.z; Bs[lk + 7][lr] = w1.w;
        __syncthreads();
#pragma unroll
        for (int k = 0; k < GBK; ++k) {
            const float4 av0 = *(const float4*)&As[k][ty * 8];
            const float4 av1 = *(const float4*)&As[k][ty * 8 + 4];
            const float4 bv0 = *(const float4*)&Bs[k][tx * 8];
            const float4 bv1 = *(const float4*)&Bs[k][tx * 8 + 4];
            const float am[8] = {av0.x, av0.y, av0.z, av0.w, av1.x, av1.y, av1.z, av1.w};
            const float bn[8] = {bv0.x, bv0.y, bv0.z, bv0.w, bv1.x, bv1.y, bv1.z, bv1.w};
#pragma unroll
            for (int i = 0; i < 8; ++i)
#pragma unroll
                for (int jj = 0; jj < 8; ++jj)
                    acc[i][jj] = fmaf(am[i], bn[jj], acc[i][jj]);
        }
    }
    const float4 bias0 = *(const float4*)&b0[n0 + tx * 8];
    const float4 bias1 = *(const float4*)&b0[n0 + tx * 8 + 4];
#pragma unroll
    for (int i = 0; i < 8; ++i) {
        const int m = m0 + ty * 8 + i;
        float4 v0, v1;
        v0.x = acc[i][0] + bias0.x; v0.y = acc[i][1] + bias0.y;
        v0.z = acc[i][2] + bias0.z; v0.w = acc[i][3] + bias0.w;
        v1.x = acc[i][4] + bias1.x; v1.y = acc[i][5] + bias1.y;
        v1.z = acc[i][6] + bias1.z; v1.w = acc[i][7] + bias1.w;
        *(float4*)&xg0[(size_t)m * G4H + n0 + tx * 8] = v0;
        *(float4*)&xg0[(size_t)m * G4H + n0 + tx * 8 + 4] = v1;
    }
}

/* ---------------- Kernel 2: 3-stage flag-synced LSTM ----------------
 * 192 blocks = 3 layers x 64 blocks. Block owns 4 cells (16 gate-rows) x all 64 b.
 * 512 threads = 8 waves; wave w owns k-chunk [32w, 32w+32).
 * Weight addresses made uniform-by-construction via readfirstlane -> s_load (K$),
 * SGPR operand feeds v_fma directly. All h-ring loads issued as one batch of 8B
 * agent atomics (pair-interleaved layout) -> single LLC round-trip per step. */
__global__ __launch_bounds__(512) void lstm_cells(
    const float* __restrict__ xg0,
    const float* __restrict__ Whh0,
    const float* __restrict__ Wih1, const float* __restrict__ Whh1, const float* __restrict__ b1,
    const float* __restrict__ Wih2, const float* __restrict__ Whh2, const float* __restrict__ b2,
    float* __restrict__ hring, int* __restrict__ flags)
{
    cg::grid_group grid = cg::this_grid();
    const int blk = blockIdx.x;
    const int layer = blk >> 6;        // 0..2
    const int lb = blk & 63;
    const int jbase = lb * 4;
    const int tid = threadIdx.x;
    const int w = tid >> 6;            // wave index 0..7
    const int b = tid & 63;            // lane == batch
    const int kbase = w * 32;

    __shared__ float red[16 * 8 * 64]; // [row][wave][b] = 32 KB

    const float* Wih = (layer == 1) ? Wih1 : Wih2;
    const float* Whh = (layer == 0) ? Whh0 : ((layer == 1) ? Whh1 : Whh2);
    const float* bias = (layer == 1) ? b1 : b2;

    // zero rings + flags (ws is poisoned); plain stores, pushed out by grid.sync's release
    for (int i = blk * 512 + tid; i < 3 * LAYER_STRIDE; i += 192 * 512) hring[i] = 0.0f;
    for (int i = blk * 512 + tid; i < 3 * TT * 64; i += 192 * 512) flags[i] = 0;

    float bs0 = 0.f, bs1 = 0.f, bs2 = 0.f, bs3 = 0.f;
    if (layer > 0 && tid < 256) {
        bs0 = bias[0 * HD + jbase + w]; bs1 = bias[1 * HD + jbase + w];
        bs2 = bias[2 * HD + jbase + w]; bs3 = bias[3 * HD + jbase + w];
    }

    float* myring = hring + layer * LAYER_STRIDE;
    const float* inring = hring + (layer - 1) * LAYER_STRIDE;

    float c = 0.0f;

    grid.sync();   // rings/flags zeroed and visible device-wide

    for (int t = 0; t < TT; ++t) {
        /* ---- layer-0 xg prefetch: issued BEFORE the poll, latency hides under it.
         * The signal fence below pins these loads above the compute. ---- */
        float xv0, xv1, xv2, xv3;
        if (layer == 0 && tid < 256) {
            const float* xg = xg0 + ((size_t)b * TT + t) * G4H + jbase + w;
            xv0 = xg[0 * HD]; xv1 = xg[1 * HD]; xv2 = xg[2 * HD]; xv3 = xg[3 * HD];
        }

        /* ---- wait for dependencies: wave 0 polls 64 per-block flags in parallel ---- */
        if (tid < 64) {
            const int* f_in  = &flags[((layer - 1) * TT + t) * 64 + tid];
            const int* f_own = &flags[(layer * TT + (t - 1)) * 64 + tid];
            const int* f_nxt = &flags[((layer + 1) * TT + (t - 4)) * 64 + tid];
            const bool need_in  = (layer > 0);
            const bool need_own = (t >= 1);
            const bool need_nxt = (layer < 2) && (t >= 4);
            for (;;) {
                int ok = 1;
                if (need_in)  ok &= __hip_atomic_load(f_in,  __ATOMIC_RELAXED, __HIP_MEMORY_SCOPE_AGENT);
                if (need_own) ok &= __hip_atomic_load(f_own, __ATOMIC_RELAXED, __HIP_MEMORY_SCOPE_AGENT);
                if (need_nxt) ok &= __hip_atomic_load(f_nxt, __ATOMIC_RELAXED, __HIP_MEMORY_SCOPE_AGENT);
                if (__all(ok)) break;
                __builtin_amdgcn_s_sleep(1);
            }
        }
        __syncthreads();
        __atomic_signal_fence(__ATOMIC_SEQ_CST);

        /* ---- ALL h-ring loads issued up-front: one LLC round-trip ---- */
        float hv[32];
        {
            const float* hpv = myring + (size_t)((t + 3) & 3) * SLOT_STRIDE
                             + (size_t)(16 * w) * 128 + b * 2;
#pragma unroll
            for (int u2 = 0; u2 < 16; ++u2) {
                const float2 v = ld_agent2(hpv + u2 * 128);
                hv[2 * u2] = v.x; hv[2 * u2 + 1] = v.y;
            }
        }
        float gv[32];
        if (layer > 0) {
            const float* hin = inring + (size_t)(t & 3) * SLOT_STRIDE
                             + (size_t)(16 * w) * 128 + b * 2;
#pragma unroll
            for (int u2 = 0; u2 < 16; ++u2) {
                const float2 v = ld_agent2(hin + u2 * 128);
                gv[2 * u2] = v.x; gv[2 * u2 + 1] = v.y;
            }
        }

        float acc[16];
#pragma unroll
        for (int r = 0; r < 16; ++r) acc[r] = 0.0f;

        /* ---- hh partials: weights via uniform (scalar) pointers ---- */
#pragma unroll
        for (int kk = 0; kk < 32; kk += 16) {
#pragma unroll
            for (int jj = 0; jj < 4; ++jj)
#pragma unroll
                for (int g = 0; g < 4; ++g) {
                    const float* wr = Whh + __builtin_amdgcn_readfirstlane(
                        (g * HD + jbase + jj) * HD + kbase + kk);
                    float a = acc[jj * 4 + g];
#pragma unroll
                    for (int u = 0; u < 16; ++u) a = fmaf(wr[u], hv[kk + u], a);
                    acc[jj * 4 + g] = a;
                }
        }
        /* ---- ih partials over h_{l-1}[t] (layers 1,2) ---- */
        if (layer > 0) {
#pragma unroll
            for (int kk = 0; kk < 32; kk += 16) {
#pragma unroll
                for (int jj = 0; jj < 4; ++jj)
#pragma unroll
                    for (int g = 0; g < 4; ++g) {
                        const float* wr = Wih + __builtin_amdgcn_readfirstlane(
                            (g * HD + jbase + jj) * HD + kbase + kk);
                        float a = acc[jj * 4 + g];
#pragma unroll
                        for (int u = 0; u < 16; ++u) a = fmaf(wr[u], gv[kk + u], a);
                        acc[jj * 4 + g] = a;
                    }
            }
        }

        /* ---- cross-wave reduction via LDS: red[row][wave][b] ---- */
#pragma unroll
        for (int r = 0; r < 16; ++r) red[(r * 8 + w) * 64 + b] = acc[r];
        __syncthreads();

        /* ---- cell update: first 4 waves, thread = (cell j = w, b) ---- */
        if (tid < 256) {
            float a0, a1, a2, a3;
            if (layer == 0) { a0 = xv0; a1 = xv1; a2 = xv2; a3 = xv3; }
            else            { a0 = bs0; a1 = bs1; a2 = bs2; a3 = bs3; }
#pragma unroll
            for (int ww = 0; ww < 8; ++ww) {
                a0 += red[((w * 4 + 0) * 8 + ww) * 64 + b];
                a1 += red[((w * 4 + 1) * 8 + ww) * 64 + b];
                a2 += red[((w * 4 + 2) * 8 + ww) * 64 + b];
                a3 += red[((w * 4 + 3) * 8 + ww) * 64 + b];
            }
            const float ig = sigmoidf_(a0);
            const float fg = sigmoidf_(a1);
            const float gg = tanhf_(a2);
            const float og = sigmoidf_(a3);
            c = fg * c + ig * gg;
            const float h = og * tanhf_(c);
            /* j = jbase + w -> pair layout: (j>>1)*128 + b*2 + (j&1) */
            st_agent(&myring[(size_t)(t & 3) * SLOT_STRIDE
                             + (size_t)(lb * 2 + (w >> 1)) * 128 + b * 2 + (w & 1)], h);
        }

        __syncthreads();   // all waves' h stores drained (vmcnt(0)) before flag
        if (tid == 0) {
            __hip_atomic_store(&flags[(layer * TT + t) * 64 + lb], 1,
                               __ATOMIC_RELAXED, __HIP_MEMORY_SCOPE_AGENT);
        }
    }
}

/* ---------------- Kernel 3: FC head on h2[T-1] (pair layout) ---------------- */
__global__ __launch_bounds__(256) void classifier_k(
    const float* __restrict__ hring,
    const float* __restrict__ W1, const float* __restrict__ bfc1,
    const float* __restrict__ W2, const float* __restrict__ bfc2,
    float* __restrict__ out)
{
    __shared__ float z[BB * 128];
    const float* h2T = hring + 2 * LAYER_STRIDE + (size_t)((TT - 1) & 3) * SLOT_STRIDE;
    const int tid = threadIdx.x;
    for (int idx = tid; idx < BB * 128; idx += 256) {
        const int bb = idx >> 7;
        const int n = idx & 127;
        float acc = bfc1[n];
        const float* wr = W1 + (size_t)n * HD;
        for (int k2 = 0; k2 < HD / 2; ++k2) {
            const float2 hvv = *(const float2*)&h2T[k2 * 128 + bb * 2];
            acc = fmaf(hvv.x, wr[2 * k2], acc);
            acc = fmaf(hvv.y, wr[2 * k2 + 1], acc);
        }
        z[bb * 128 + n] = fmaxf(acc, 0.0f);
    }
    __syncthreads();
    for (int idx = tid; idx < BB * NCLS; idx += 256) {
        const int bb = idx >> 3;
        const int n = idx & 7;
        float acc = bfc2[n];
        const float* zr = &z[bb * 128];
        const float* wr = W2 + (size_t)n * 128;
        for (int k = 0; k < 128; k += 4) {
            const float4 zv = *(const float4*)&zr[k];
            const float4 wv = *(const float4*)&wr[k];
            acc = fmaf(zv.x, wv.x, acc); acc = fmaf(zv.y, wv.y, acc);
            acc = fmaf(zv.z, wv.z, acc); acc = fmaf(zv.w, wv.w, acc);
        }
        out[idx] = acc;
    }
}

extern "C" void kernel_launch(void* const* d_in, const int* in_sizes, int n_in,
                              void* d_out, int out_size, void* d_ws, size_t ws_size,
                              hipStream_t stream) {
    const float* x    = (const float*)d_in[0];
    const float* Wih0 = (const float*)d_in[1];
    const float* Whh0 = (const float*)d_in[2];
    const float* b0   = (const float*)d_in[3];
    const float* Wih1 = (const float*)d_in[4];
    const float* Whh1 = (const float*)d_in[5];
    const float* b1   = (const float*)d_in[6];
    const float* Wih2 = (const float*)d_in[7];
    const float* Whh2 = (const float*)d_in[8];
    const float* b2   = (const float*)d_in[9];
    const float* W1   = (const float*)d_in[10];
    const float* bfc1 = (const float*)d_in[11];
    const float* W2   = (const float*)d_in[12];
    const float* bfc2 = (const float*)d_in[13];

    float* xg0   = (float*)d_ws;                       // B*T*4H fp32 = 134.2 MB
    float* hring = xg0 + (size_t)BB * TT * G4H;        // 786 KB
    int*   flags = (int*)(hring + 3 * LAYER_STRIDE);   // 3*512*64 ints = 393 KB

    xg0_gemm<<<dim3(G4H / GBN, (BB * TT) / GBM), 256, 0, stream>>>(x, Wih0, b0, xg0);

    const float* xg0c = xg0;
    float* hr = hring;
    int* fl = flags;
    void* args[] = {
        (void*)&xg0c, (void*)&Whh0,
        (void*)&Wih1, (void*)&Whh1, (void*)&b1,
        (void*)&Wih2, (void*)&Whh2, (void*)&b2,
        (void*)&hr, (void*)&fl
    };
    hipLaunchCooperativeKernel((void*)lstm_cells, dim3(192), dim3(512), args, 0, stream);

    classifier_k<<<1, 256, 0, stream>>>(hring, W1, bfc1, W2, bfc2, (float*)d_out);
}